// Round 7
// baseline (784.329 us; speedup 1.0000x reference)
//
#include <hip/hip_runtime.h>

#define D 128
#define FLT_BIG 3.402823466e+38f

typedef __attribute__((ext_vector_type(8))) short short8;
typedef __attribute__((ext_vector_type(4))) float floatx4;

union __align__(16) U8 { unsigned short u[8]; short8 v; };

__device__ __forceinline__ unsigned short f2bf(float f) {
    unsigned u = __float_as_uint(f);
    unsigned r = (u + 0x7FFFu + ((u >> 16) & 1u)) >> 16;
    return (unsigned short)r;
}
__device__ __forceinline__ float bf2f(unsigned short s) {
    return __uint_as_float(((unsigned)s) << 16);
}

// ---------------- CSR build ----------------

__global__ void zero2_kernel(int* __restrict__ cnt, int* __restrict__ fill, int n) {
    int i = blockIdx.x * blockDim.x + threadIdx.x;
    if (i < n) { cnt[i] = 0; fill[i] = 0; }
}

__global__ void hist_kernel(const int* __restrict__ dst, int* __restrict__ cnt, int nE) {
    int i = blockIdx.x * blockDim.x + threadIdx.x;
    if (i < nE) atomicAdd(&cnt[dst[i]], 1);
}

__global__ void scanA_kernel(const int* __restrict__ cnt, int* __restrict__ chunksum, int n) {
    __shared__ int sm[256];
    int t = threadIdx.x;
    int i = blockIdx.x * 256 + t;
    sm[t] = (i < n) ? cnt[i] : 0;
    __syncthreads();
    for (int s = 128; s > 0; s >>= 1) {
        if (t < s) sm[t] += sm[t + s];
        __syncthreads();
    }
    if (t == 0) chunksum[blockIdx.x] = sm[0];
}

__global__ void scanB_kernel(const int* __restrict__ chunksum, int* __restrict__ chunkoff, int nc) {
    __shared__ int sm[256];
    int t = threadIdx.x;
    int v = (t < nc) ? chunksum[t] : 0;
    sm[t] = v;
    __syncthreads();
    for (int s = 1; s < 256; s <<= 1) {
        int add = (t >= s) ? sm[t - s] : 0;
        __syncthreads();
        sm[t] += add;
        __syncthreads();
    }
    if (t < nc) chunkoff[t] = sm[t] - v;
}

__global__ void scanC_kernel(const int* __restrict__ cnt, const int* __restrict__ chunkoff,
                             int* __restrict__ off, int n) {
    __shared__ int sm[256];
    int t = threadIdx.x;
    int i = blockIdx.x * 256 + t;
    int v = (i < n) ? cnt[i] : 0;
    sm[t] = v;
    __syncthreads();
    for (int s = 1; s < 256; s <<= 1) {
        int add = (t >= s) ? sm[t - s] : 0;
        __syncthreads();
        sm[t] += add;
        __syncthreads();
    }
    if (i < n) off[i] = chunkoff[blockIdx.x] + sm[t] - v;
}

__global__ void scatter_kernel(const int* __restrict__ dst, const int* __restrict__ off,
                               int* __restrict__ fill, int* __restrict__ perm, int nE) {
    int i = blockIdx.x * blockDim.x + threadIdx.x;
    if (i < nE) {
        int d = dst[i];
        int p = off[d] + atomicAdd(&fill[d], 1);
        perm[p] = i;
    }
}

// ---------------- pack W into MFMA B-fragment order ----------------
// B-frag elem j, lane l, tile (nt, ks): W[k = ks*32 + (l>>4)*8 + j][col = nt*16 + (l&15)]
// stored at ((nt*(K/32) + ks)*64 + l)*8 + j

__global__ void pack_kernel(const float* __restrict__ W0, const float* __restrict__ W1,
                            int Kdim, unsigned short* __restrict__ hi,
                            unsigned short* __restrict__ lo) {
    int ksn = Kdim >> 5;
    int nt = blockIdx.x / ksn;
    int ks = blockIdx.x % ksn;
    int l = threadIdx.x;
    int c = nt * 16 + (l & 15);
    const float* Wsrc = (c < 128) ? W0 : W1;
    int cc = c & 127;
    int kbase = ks * 32 + (l >> 4) * 8;
    size_t o = ((size_t)blockIdx.x * 64 + l) * 8;
#pragma unroll
    for (int j = 0; j < 8; ++j) {
        float w = Wsrc[(size_t)(kbase + j) * 128 + cc];
        unsigned short h = f2bf(w);
        hi[o + j] = h;
        if (lo) lo[o + j] = f2bf(w - bf2f(h));
    }
}

// ---------------- qproj via MFMA: 64 nodes / 256-thread block ----------------

__global__ __launch_bounds__(256, 2) void qproj_mfma(
        const float* __restrict__ q,
        const unsigned short* __restrict__ Bhi, const unsigned short* __restrict__ Blo,
        unsigned short* __restrict__ qp, int nNodes) {
    __shared__ __align__(16) unsigned short qhi[64][128];
    __shared__ __align__(16) unsigned short qlo[64][128];
    int t = threadIdx.x;
    int n0 = blockIdx.x * 64;
    {
        int e = t >> 2, sub = t & 3;
        int node = n0 + e;
        for (int cc = 0; cc < 4; ++cc) {
            int chunk = sub * 4 + cc;
            U8 H, L;
            if (node < nNodes) {
                const float* srcp = q + (size_t)node * 128 + chunk * 8;
                float4 v0 = *(const float4*)(srcp);
                float4 v1 = *(const float4*)(srcp + 4);
                float vv[8] = {v0.x, v0.y, v0.z, v0.w, v1.x, v1.y, v1.z, v1.w};
#pragma unroll
                for (int j = 0; j < 8; ++j) {
                    unsigned short h = f2bf(vv[j]);
                    H.u[j] = h; L.u[j] = f2bf(vv[j] - bf2f(h));
                }
            } else {
#pragma unroll
                for (int j = 0; j < 8; ++j) { H.u[j] = 0; L.u[j] = 0; }
            }
            int sc = chunk ^ (e & 7);
            *reinterpret_cast<short8*>(&qhi[e][sc * 8]) = H.v;
            *reinterpret_cast<short8*>(&qlo[e][sc * 8]) = L.v;
        }
    }
    __syncthreads();
    int w = t >> 6, l = t & 63;
    int lrow = l & 15, lk = l >> 4;
    floatx4 acc[4][2];
#pragma unroll
    for (int mt = 0; mt < 4; ++mt)
#pragma unroll
        for (int n = 0; n < 2; ++n) acc[mt][n] = (floatx4){0.f, 0.f, 0.f, 0.f};
    for (int ks = 0; ks < 4; ++ks) {
        short8 ah[4], al[4];
#pragma unroll
        for (int mt = 0; mt < 4; ++mt) {
            int row = mt * 16 + lrow;
            int sc = (ks * 4 + lk) ^ (row & 7);
            ah[mt] = *reinterpret_cast<const short8*>(&qhi[row][sc * 8]);
            al[mt] = *reinterpret_cast<const short8*>(&qlo[row][sc * 8]);
        }
#pragma unroll
        for (int ntl = 0; ntl < 2; ++ntl) {
            int ntg = w * 2 + ntl;
            size_t bo = ((size_t)(ntg * 4 + ks) * 64 + l) * 8;
            short8 bh = *reinterpret_cast<const short8*>(Bhi + bo);
            short8 bl = *reinterpret_cast<const short8*>(Blo + bo);
#pragma unroll
            for (int mt = 0; mt < 4; ++mt) {
                acc[mt][ntl] = __builtin_amdgcn_mfma_f32_16x16x32_bf16(ah[mt], bh, acc[mt][ntl], 0, 0, 0);
                acc[mt][ntl] = __builtin_amdgcn_mfma_f32_16x16x32_bf16(al[mt], bh, acc[mt][ntl], 0, 0, 0);
                acc[mt][ntl] = __builtin_amdgcn_mfma_f32_16x16x32_bf16(ah[mt], bl, acc[mt][ntl], 0, 0, 0);
            }
        }
    }
#pragma unroll
    for (int mt = 0; mt < 4; ++mt)
#pragma unroll
        for (int ntl = 0; ntl < 2; ++ntl) {
            int col = (w * 2 + ntl) * 16 + lrow;
#pragma unroll
            for (int r = 0; r < 4; ++r) {
                int row = mt * 16 + lk * 4 + r;
                int node = n0 + row;
                if (node < nNodes) qp[(size_t)node * 128 + col] = f2bf(acc[mt][ntl][r]);
            }
        }
}

// ---------------- fused edge + stats + PNA + Wo + LN: 8 nodes / 256-thread block ----------------

__global__ __launch_bounds__(256, 4) void edge_fused(
        const float* __restrict__ E, const float* __restrict__ R,
        const unsigned short* __restrict__ qp,
        const unsigned short* __restrict__ Bhi, const unsigned short* __restrict__ Blo,
        const unsigned short* __restrict__ Wop,
        const float* __restrict__ deg,
        const int* __restrict__ src, const int* __restrict__ rel,
        const int* __restrict__ dst, const int* __restrict__ perm,
        const int* __restrict__ off,
        const float* __restrict__ q, const float* __restrict__ ln_g,
        const float* __restrict__ ln_b, float* __restrict__ out,
        int nNodes, int nE) {

    __shared__ __align__(16) unsigned short msgb[2][32][128];  // 16KB; reused: V f32 [32][128]; then aggb bf16 [16][512]
    __shared__ __align__(16) unsigned short Kb[32][128];       // 8KB; reused: hb f32 [8][128]
    __shared__ float alph[32][8];                              // sigmoid * deg
    __shared__ __align__(16) unsigned short qpl[8][128];
    __shared__ float sdeg[32];
    __shared__ int sdst[32];
    __shared__ int noff[9];

    int t = threadIdx.x;
    int n0 = blockIdx.x * 8;

    if (t < 9) {
        int idx = n0 + t;
        noff[t] = (idx < nNodes) ? off[idx] : nE;
    }
    {
        int ln = t >> 5, g = t & 31;
        int node = n0 + ln;
        ushort4 v;
        if (node < nNodes) v = *(const ushort4*)(qp + (size_t)node * 128 + g * 4);
        else { v.x = 0; v.y = 0; v.z = 0; v.w = 0; }
        *(ushort4*)(&qpl[ln][g * 4]) = v;
    }
    __syncthreads();

    int eb = noff[0], ee = noff[8];

    int lnS = t >> 5, gS = t & 31;
    float sSx = 0.f, sSy = 0.f, sSz = 0.f, sSw = 0.f;
    float sQx = 0.f, sQy = 0.f, sQz = 0.f, sQw = 0.f;
    float sXx = -FLT_BIG, sXy = -FLT_BIG, sXz = -FLT_BIG, sXw = -FLT_BIG;
    float sNx = FLT_BIG, sNy = FLT_BIG, sNz = FLT_BIG, sNw = FLT_BIG;

    int w = t >> 6, l = t & 63;
    int lrow = l & 15, lk = l >> 4;
    float* Vlds = (float*)msgb;

    for (int c0 = eb; c0 < ee; c0 += 32) {
        // ---- stage msg (hi/lo bf16) ----
        {
            int e = t >> 3, sub = t & 7;
            int ei = c0 + e;
            bool ok = (ei < ee);
            int p = ok ? perm[ei] : 0;
            if (sub == 0) sdst[e] = ok ? (dst[p] - n0) : -1;
            if (sub == 1) sdeg[e] = ok ? deg[p] : 0.f;
            const float* Erow = E + (size_t)(ok ? src[p] : 0) * 128;
            const float* Rrow = R + (size_t)(ok ? rel[p] : 0) * 128;
#pragma unroll
            for (int cc = 0; cc < 2; ++cc) {
                int chunk = sub * 2 + cc;
                U8 H, L;
                if (ok) {
                    float4 a0 = *(const float4*)(Erow + chunk * 8);
                    float4 a1 = *(const float4*)(Erow + chunk * 8 + 4);
                    float4 b0 = *(const float4*)(Rrow + chunk * 8);
                    float4 b1 = *(const float4*)(Rrow + chunk * 8 + 4);
                    float m[8] = {a0.x * b0.x, a0.y * b0.y, a0.z * b0.z, a0.w * b0.w,
                                  a1.x * b1.x, a1.y * b1.y, a1.z * b1.z, a1.w * b1.w};
#pragma unroll
                    for (int j = 0; j < 8; ++j) {
                        unsigned short h = f2bf(m[j]);
                        H.u[j] = h; L.u[j] = f2bf(m[j] - bf2f(h));
                    }
                } else {
#pragma unroll
                    for (int j = 0; j < 8; ++j) { H.u[j] = 0; L.u[j] = 0; }
                }
                int sc = chunk ^ (e & 7);
                *reinterpret_cast<short8*>(&msgb[0][e][sc * 8]) = H.v;
                *reinterpret_cast<short8*>(&msgb[1][e][sc * 8]) = L.v;
            }
        }
        __syncthreads();

        // ---- GEMM: 3-pass hi/lo for both K and V tiles (matches R4-proven numerics) ----
        floatx4 acc[2][4];
#pragma unroll
        for (int mt = 0; mt < 2; ++mt)
#pragma unroll
            for (int n = 0; n < 4; ++n) acc[mt][n] = (floatx4){0.f, 0.f, 0.f, 0.f};
        for (int ks = 0; ks < 4; ++ks) {
            short8 ah[2], al[2];
#pragma unroll
            for (int mt = 0; mt < 2; ++mt) {
                int row = mt * 16 + lrow;
                int sc = (ks * 4 + lk) ^ (row & 7);
                ah[mt] = *reinterpret_cast<const short8*>(&msgb[0][row][sc * 8]);
                al[mt] = *reinterpret_cast<const short8*>(&msgb[1][row][sc * 8]);
            }
#pragma unroll
            for (int ntl = 0; ntl < 4; ++ntl) {
                int ntg = (ntl < 2) ? (w * 2 + ntl) : (8 + w * 2 + (ntl - 2));
                size_t bo = ((size_t)(ntg * 4 + ks) * 64 + l) * 8;
                short8 bh = *reinterpret_cast<const short8*>(Bhi + bo);
                short8 bl = *reinterpret_cast<const short8*>(Blo + bo);
#pragma unroll
                for (int mt = 0; mt < 2; ++mt) {
                    acc[mt][ntl] = __builtin_amdgcn_mfma_f32_16x16x32_bf16(ah[mt], bh, acc[mt][ntl], 0, 0, 0);
                    acc[mt][ntl] = __builtin_amdgcn_mfma_f32_16x16x32_bf16(al[mt], bh, acc[mt][ntl], 0, 0, 0);
                    acc[mt][ntl] = __builtin_amdgcn_mfma_f32_16x16x32_bf16(ah[mt], bl, acc[mt][ntl], 0, 0, 0);
                }
            }
        }
        __syncthreads();   // msgb A-reads done; safe to overwrite with V

        // ---- writeback K (bf16) / V (f32, overlaying msgb) ----
#pragma unroll
        for (int mt = 0; mt < 2; ++mt)
#pragma unroll
            for (int ntl = 0; ntl < 4; ++ntl) {
                int ntg = (ntl < 2) ? (w * 2 + ntl) : (8 + w * 2 + (ntl - 2));
                int col = ntg * 16 + lrow;
#pragma unroll
                for (int r = 0; r < 4; ++r) {
                    int row = mt * 16 + lk * 4 + r;
                    int key = ((row >> 2) & 3) << 4;
                    float v = acc[mt][ntl][r];
                    if (col < 128) Kb[row][col ^ key] = f2bf(v);
                    else Vlds[row * 128 + ((col - 128) ^ key)] = v;
                }
            }
        __syncthreads();

        // ---- alpha: thread = (edge, head) ----
        {
            int e = t >> 3, h = t & 7;
            int ln = sdst[e];
            float wv = 0.f;
            if (ln >= 0) {
                int key = ((e >> 2) & 3) << 4;
                int cb = (h * 16) ^ key;
                U8 k0, k1, q0, q1;
                k0.v = *reinterpret_cast<const short8*>(&Kb[e][cb]);
                k1.v = *reinterpret_cast<const short8*>(&Kb[e][cb + 8]);
                q0.v = *reinterpret_cast<const short8*>(&qpl[ln][h * 16]);
                q1.v = *reinterpret_cast<const short8*>(&qpl[ln][h * 16 + 8]);
                float a = 0.f;
#pragma unroll
                for (int j = 0; j < 8; ++j) {
                    a = fmaf(bf2f(k0.u[j]), bf2f(q0.u[j]), a);
                    a = fmaf(bf2f(k1.u[j]), bf2f(q1.u[j]), a);
                }
                float alphav = a * 0.25f;                 // / sqrt(16)
                wv = sdeg[e] / (1.f + __expf(-alphav));   // sigmoid * deg
            }
            alph[e][h] = wv;
        }
        __syncthreads();

        // ---- stats: thread = (node lnS, cols 4gS..4gS+3) ----
        {
            int lo = max(noff[lnS], c0);
            int hi = min(noff[lnS + 1], c0 + 32);
            for (int ei2 = lo; ei2 < hi; ++ei2) {
                int el = ei2 - c0;
                int key = ((el >> 2) & 3) << 4;
                float4 v4 = *(const float4*)(Vlds + el * 128 + ((gS * 4) ^ key));
                float aa = alph[el][gS >> 2];
                float xx = v4.x * aa, xy = v4.y * aa, xz = v4.z * aa, xw = v4.w * aa;
                sSx += xx; sSy += xy; sSz += xz; sSw += xw;
                sQx = fmaf(xx, xx, sQx); sQy = fmaf(xy, xy, sQy);
                sQz = fmaf(xz, xz, sQz); sQw = fmaf(xw, xw, sQw);
                sXx = fmaxf(sXx, xx); sXy = fmaxf(sXy, xy);
                sXz = fmaxf(sXz, xz); sXw = fmaxf(sXw, xw);
                sNx = fminf(sNx, xx); sNy = fminf(sNy, xy);
                sNz = fminf(sNz, xz); sNw = fminf(sNw, xw);
            }
        }
        __syncthreads();
    }

    // ---- build agg tile (bf16, MFMA-A layout, rows 8..15 zero) ----
    unsigned short* aggb = (unsigned short*)msgb;   // [16][512]
    *reinterpret_cast<short8*>(aggb + 8 * 512 + t * 16) = (short8){0,0,0,0,0,0,0,0};
    *reinterpret_cast<short8*>(aggb + 8 * 512 + t * 16 + 8) = (short8){0,0,0,0,0,0,0,0};
    {
        int c = noff[lnS + 1] - noff[lnS];
        float invc = (c > 0) ? 1.f / (float)c : 0.f;
        float vals[4][4];
        vals[0][0] = sSx * invc; vals[0][1] = sSy * invc; vals[0][2] = sSz * invc; vals[0][3] = sSw * invc;
        vals[1][0] = (c > 0) ? sXx : 0.f; vals[1][1] = (c > 0) ? sXy : 0.f;
        vals[1][2] = (c > 0) ? sXz : 0.f; vals[1][3] = (c > 0) ? sXw : 0.f;
        vals[2][0] = (c > 0) ? sNx : 0.f; vals[2][1] = (c > 0) ? sNy : 0.f;
        vals[2][2] = (c > 0) ? sNz : 0.f; vals[2][3] = (c > 0) ? sNw : 0.f;
        vals[3][0] = sqrtf(fmaxf(sQx - sSx * sSx, 1e-8f));
        vals[3][1] = sqrtf(fmaxf(sQy - sSy * sSy, 1e-8f));
        vals[3][2] = sqrtf(fmaxf(sQz - sSz * sSz, 1e-8f));
        vals[3][3] = sqrtf(fmaxf(sQw - sSw * sSw, 1e-8f));
#pragma unroll
        for (int s = 0; s < 4; ++s) {
            int chunk = s * 16 + (gS >> 1);
            int pos = ((chunk ^ (lnS & 7)) << 3) + ((gS & 1) * 4);
            ushort4 o;
            o.x = f2bf(vals[s][0]); o.y = f2bf(vals[s][1]);
            o.z = f2bf(vals[s][2]); o.w = f2bf(vals[s][3]);
            *(ushort4*)(aggb + lnS * 512 + pos) = o;
        }
    }
    __syncthreads();

    // ---- Wo MFMA: m-tile 16 (rows 0..7 real), n = 128, K = 512 ----
    floatx4 acc2[2];
    acc2[0] = (floatx4){0.f, 0.f, 0.f, 0.f};
    acc2[1] = (floatx4){0.f, 0.f, 0.f, 0.f};
    for (int ks = 0; ks < 16; ++ks) {
        int sc = (ks * 4 + lk) ^ (lrow & 7);
        short8 a = *reinterpret_cast<const short8*>(aggb + lrow * 512 + sc * 8);
#pragma unroll
        for (int ntl = 0; ntl < 2; ++ntl) {
            int ntg = w * 2 + ntl;
            short8 b = *reinterpret_cast<const short8*>(Wop + ((size_t)(ntg * 16 + ks) * 64 + l) * 8);
            acc2[ntl] = __builtin_amdgcn_mfma_f32_16x16x32_bf16(a, b, acc2[ntl], 0, 0, 0);
        }
    }

    // ---- residual into hb (overlay Kb region) ----
    float* hb = (float*)Kb;   // [8][128]
#pragma unroll
    for (int ntl = 0; ntl < 2; ++ntl) {
        int col = (w * 2 + ntl) * 16 + lrow;
#pragma unroll
        for (int r = 0; r < 4; ++r) {
            int row = lk * 4 + r;
            if (row < 8) {
                int node = n0 + row;
                float h = acc2[ntl][r] + ((node < nNodes) ? q[(size_t)node * 128 + col] : 0.f);
                hb[row * 128 + col] = h;
            }
        }
    }
    __syncthreads();

    // ---- LayerNorm + out ----
    {
        int node = n0 + lnS;
        float4 h4 = *(const float4*)(hb + lnS * 128 + gS * 4);
        float ps = h4.x + h4.y + h4.z + h4.w;
        ps += __shfl_xor(ps, 1);
        ps += __shfl_xor(ps, 2);
        ps += __shfl_xor(ps, 4);
        ps += __shfl_xor(ps, 8);
        ps += __shfl_xor(ps, 16);
        float mu = ps * (1.f / 128.f);
        float dx = h4.x - mu, dy = h4.y - mu, dz = h4.z - mu, dw = h4.w - mu;
        float pv = dx * dx + dy * dy + dz * dz + dw * dw;
        pv += __shfl_xor(pv, 1);
        pv += __shfl_xor(pv, 2);
        pv += __shfl_xor(pv, 4);
        pv += __shfl_xor(pv, 8);
        pv += __shfl_xor(pv, 16);
        float rr = rsqrtf(pv * (1.f / 128.f) + 1e-5f);
        if (node < nNodes) {
            float4 gv = *(const float4*)(ln_g + gS * 4);
            float4 bv = *(const float4*)(ln_b + gS * 4);
            float4 o;
            o.x = dx * rr * gv.x + bv.x;
            o.y = dy * rr * gv.y + bv.y;
            o.z = dz * rr * gv.z + bv.z;
            o.w = dw * rr * gv.w + bv.w;
            *(float4*)(out + (size_t)node * 128 + gS * 4) = o;
        }
    }
}

// ---------------- launch ----------------

extern "C" void kernel_launch(void* const* d_in, const int* in_sizes, int n_in,
                              void* d_out, int out_size, void* d_ws, size_t ws_size,
                              hipStream_t stream) {
    const float* q    = (const float*)d_in[0];
    const float* E    = (const float*)d_in[1];
    const float* R    = (const float*)d_in[2];
    const float* Wq   = (const float*)d_in[3];
    const float* Wk   = (const float*)d_in[4];
    const float* Wv   = (const float*)d_in[5];
    const float* Wo   = (const float*)d_in[6];
    const float* ln_g = (const float*)d_in[7];
    const float* ln_b = (const float*)d_in[8];
    const float* deg  = (const float*)d_in[9];
    const int* src    = (const int*)d_in[10];
    const int* rel    = (const int*)d_in[11];
    const int* dst    = (const int*)d_in[12];
    int nNodes = in_sizes[0] / D;   // 50000
    int nEdges = in_sizes[10];      // 500000
    float* out = (float*)d_out;

    // NOTE: w is char*, so every increment is in BYTES (R5 bug: dropped *2 on short buffers).
    char* w = (char*)d_ws;
    size_t nd = (size_t)nNodes * D;
    unsigned short* qp = (unsigned short*)w; w += nd * 2;                    // 12.8 MB
    int* cnt      = (int*)w;                 w += (size_t)nNodes * 4;
    int* off      = (int*)w;                 w += (size_t)nNodes * 4;
    int* fill     = (int*)w;                 w += (size_t)nNodes * 4;
    int* perm     = (int*)w;                 w += (size_t)nEdges * 4;        // 2 MB
    int* chunksum = (int*)w;                 w += 256 * 4;
    int* chunkoff = (int*)w;                 w += 256 * 4;
    unsigned short* Wp_hi  = (unsigned short*)w; w += 16 * 4 * 64 * 8 * 2;   // 64 KB (bytes)
    unsigned short* Wp_lo  = (unsigned short*)w; w += 16 * 4 * 64 * 8 * 2;
    unsigned short* Wqp_hi = (unsigned short*)w; w += 8 * 4 * 64 * 8 * 2;    // 32 KB
    unsigned short* Wqp_lo = (unsigned short*)w; w += 8 * 4 * 64 * 8 * 2;
    unsigned short* Wop    = (unsigned short*)w; w += 8 * 16 * 64 * 8 * 2;   // 128 KB
    // total ~15.8 MB

    int nChunks = (nNodes + 255) / 256;

    zero2_kernel<<<(nNodes + 255) / 256, 256, 0, stream>>>(cnt, fill, nNodes);
    hist_kernel<<<(nEdges + 255) / 256, 256, 0, stream>>>(dst, cnt, nEdges);
    scanA_kernel<<<nChunks, 256, 0, stream>>>(cnt, chunksum, nNodes);
    scanB_kernel<<<1, 256, 0, stream>>>(chunksum, chunkoff, nChunks);
    scanC_kernel<<<nChunks, 256, 0, stream>>>(cnt, chunkoff, off, nNodes);
    scatter_kernel<<<(nEdges + 255) / 256, 256, 0, stream>>>(dst, off, fill, perm, nEdges);

    pack_kernel<<<16 * 4, 64, 0, stream>>>(Wk, Wv, 128, Wp_hi, Wp_lo);
    pack_kernel<<<8 * 4, 64, 0, stream>>>(Wq, Wq, 128, Wqp_hi, Wqp_lo);
    pack_kernel<<<8 * 16, 64, 0, stream>>>(Wo, Wo, 512, Wop, (unsigned short*)nullptr);

    qproj_mfma<<<(nNodes + 63) / 64, 256, 0, stream>>>(q, Wqp_hi, Wqp_lo, qp, nNodes);
    edge_fused<<<(nNodes + 7) / 8, 256, 0, stream>>>(E, R, qp, Wp_hi, Wp_lo, Wop, deg,
                                                     src, rel, dst, perm, off,
                                                     q, ln_g, ln_b, out, nNodes, nEdges);
}

// Round 8
// 481.143 us; speedup vs baseline: 1.6301x; 1.6301x over previous
//
#include <hip/hip_runtime.h>

#define D 128
#define FLT_BIG 3.402823466e+38f

typedef __attribute__((ext_vector_type(8))) short short8;
typedef __attribute__((ext_vector_type(4))) float floatx4;

union __align__(16) U8 { unsigned short u[8]; short8 v; };

__device__ __forceinline__ unsigned short f2bf(float f) {
    unsigned u = __float_as_uint(f);
    unsigned r = (u + 0x7FFFu + ((u >> 16) & 1u)) >> 16;
    return (unsigned short)r;
}
__device__ __forceinline__ float bf2f(unsigned short s) {
    return __uint_as_float(((unsigned)s) << 16);
}

// ---------------- CSR build ----------------

__global__ void zero2_kernel(int* __restrict__ cnt, int* __restrict__ fill, int n) {
    int i = blockIdx.x * blockDim.x + threadIdx.x;
    if (i < n) { cnt[i] = 0; fill[i] = 0; }
}

__global__ void hist_kernel(const int* __restrict__ dst, int* __restrict__ cnt, int nE) {
    int i = blockIdx.x * blockDim.x + threadIdx.x;
    if (i < nE) atomicAdd(&cnt[dst[i]], 1);
}

__global__ void scanA_kernel(const int* __restrict__ cnt, int* __restrict__ chunksum, int n) {
    __shared__ int sm[256];
    int t = threadIdx.x;
    int i = blockIdx.x * 256 + t;
    sm[t] = (i < n) ? cnt[i] : 0;
    __syncthreads();
    for (int s = 128; s > 0; s >>= 1) {
        if (t < s) sm[t] += sm[t + s];
        __syncthreads();
    }
    if (t == 0) chunksum[blockIdx.x] = sm[0];
}

__global__ void scanB_kernel(const int* __restrict__ chunksum, int* __restrict__ chunkoff, int nc) {
    __shared__ int sm[256];
    int t = threadIdx.x;
    int v = (t < nc) ? chunksum[t] : 0;
    sm[t] = v;
    __syncthreads();
    for (int s = 1; s < 256; s <<= 1) {
        int add = (t >= s) ? sm[t - s] : 0;
        __syncthreads();
        sm[t] += add;
        __syncthreads();
    }
    if (t < nc) chunkoff[t] = sm[t] - v;
}

__global__ void scanC_kernel(const int* __restrict__ cnt, const int* __restrict__ chunkoff,
                             int* __restrict__ off, int n) {
    __shared__ int sm[256];
    int t = threadIdx.x;
    int i = blockIdx.x * 256 + t;
    int v = (i < n) ? cnt[i] : 0;
    sm[t] = v;
    __syncthreads();
    for (int s = 1; s < 256; s <<= 1) {
        int add = (t >= s) ? sm[t - s] : 0;
        __syncthreads();
        sm[t] += add;
        __syncthreads();
    }
    if (i < n) off[i] = chunkoff[blockIdx.x] + sm[t] - v;
}

__global__ void scatter_kernel(const int* __restrict__ dst, const int* __restrict__ off,
                               int* __restrict__ fill, int* __restrict__ perm, int nE) {
    int i = blockIdx.x * blockDim.x + threadIdx.x;
    if (i < nE) {
        int d = dst[i];
        int p = off[d] + atomicAdd(&fill[d], 1);
        perm[p] = i;
    }
}

// ---------------- pack W into MFMA B-fragment order ----------------
// B-frag elem j, lane l, tile (nt, ks): W[k = ks*32 + (l>>4)*8 + j][col = nt*16 + (l&15)]
// stored at ((nt*(K/32) + ks)*64 + l)*8 + j

__global__ void pack_kernel(const float* __restrict__ W0, const float* __restrict__ W1,
                            int Kdim, unsigned short* __restrict__ hi,
                            unsigned short* __restrict__ lo) {
    int ksn = Kdim >> 5;
    int nt = blockIdx.x / ksn;
    int ks = blockIdx.x % ksn;
    int l = threadIdx.x;
    int c = nt * 16 + (l & 15);
    const float* Wsrc = (c < 128) ? W0 : W1;
    int cc = c & 127;
    int kbase = ks * 32 + (l >> 4) * 8;
    size_t o = ((size_t)blockIdx.x * 64 + l) * 8;
#pragma unroll
    for (int j = 0; j < 8; ++j) {
        float w = Wsrc[(size_t)(kbase + j) * 128 + cc];
        unsigned short h = f2bf(w);
        hi[o + j] = h;
        if (lo) lo[o + j] = f2bf(w - bf2f(h));
    }
}

// ---------------- qproj via MFMA: 64 nodes / 256-thread block ----------------

__global__ __launch_bounds__(256, 2) void qproj_mfma(
        const float* __restrict__ q,
        const unsigned short* __restrict__ Bhi, const unsigned short* __restrict__ Blo,
        unsigned short* __restrict__ qp, int nNodes) {
    __shared__ __align__(16) unsigned short qhi[64][128];
    __shared__ __align__(16) unsigned short qlo[64][128];
    int t = threadIdx.x;
    int n0 = blockIdx.x * 64;
    {
        int e = t >> 2, sub = t & 3;
        int node = n0 + e;
        for (int cc = 0; cc < 4; ++cc) {
            int chunk = sub * 4 + cc;
            U8 H, L;
            if (node < nNodes) {
                const float* srcp = q + (size_t)node * 128 + chunk * 8;
                float4 v0 = *(const float4*)(srcp);
                float4 v1 = *(const float4*)(srcp + 4);
                float vv[8] = {v0.x, v0.y, v0.z, v0.w, v1.x, v1.y, v1.z, v1.w};
#pragma unroll
                for (int j = 0; j < 8; ++j) {
                    unsigned short h = f2bf(vv[j]);
                    H.u[j] = h; L.u[j] = f2bf(vv[j] - bf2f(h));
                }
            } else {
#pragma unroll
                for (int j = 0; j < 8; ++j) { H.u[j] = 0; L.u[j] = 0; }
            }
            int sc = chunk ^ (e & 7);
            *reinterpret_cast<short8*>(&qhi[e][sc * 8]) = H.v;
            *reinterpret_cast<short8*>(&qlo[e][sc * 8]) = L.v;
        }
    }
    __syncthreads();
    int w = t >> 6, l = t & 63;
    int lrow = l & 15, lk = l >> 4;
    floatx4 acc[4][2];
#pragma unroll
    for (int mt = 0; mt < 4; ++mt)
#pragma unroll
        for (int n = 0; n < 2; ++n) acc[mt][n] = (floatx4){0.f, 0.f, 0.f, 0.f};
    for (int ks = 0; ks < 4; ++ks) {
        short8 ah[4], al[4];
#pragma unroll
        for (int mt = 0; mt < 4; ++mt) {
            int row = mt * 16 + lrow;
            int sc = (ks * 4 + lk) ^ (row & 7);
            ah[mt] = *reinterpret_cast<const short8*>(&qhi[row][sc * 8]);
            al[mt] = *reinterpret_cast<const short8*>(&qlo[row][sc * 8]);
        }
#pragma unroll
        for (int ntl = 0; ntl < 2; ++ntl) {
            int ntg = w * 2 + ntl;
            size_t bo = ((size_t)(ntg * 4 + ks) * 64 + l) * 8;
            short8 bh = *reinterpret_cast<const short8*>(Bhi + bo);
            short8 bl = *reinterpret_cast<const short8*>(Blo + bo);
#pragma unroll
            for (int mt = 0; mt < 4; ++mt) {
                acc[mt][ntl] = __builtin_amdgcn_mfma_f32_16x16x32_bf16(ah[mt], bh, acc[mt][ntl], 0, 0, 0);
                acc[mt][ntl] = __builtin_amdgcn_mfma_f32_16x16x32_bf16(al[mt], bh, acc[mt][ntl], 0, 0, 0);
                acc[mt][ntl] = __builtin_amdgcn_mfma_f32_16x16x32_bf16(ah[mt], bl, acc[mt][ntl], 0, 0, 0);
            }
        }
    }
#pragma unroll
    for (int mt = 0; mt < 4; ++mt)
#pragma unroll
        for (int ntl = 0; ntl < 2; ++ntl) {
            int col = (w * 2 + ntl) * 16 + lrow;
#pragma unroll
            for (int r = 0; r < 4; ++r) {
                int row = mt * 16 + lk * 4 + r;
                int node = n0 + row;
                if (node < nNodes) qp[(size_t)node * 128 + col] = f2bf(acc[mt][ntl][r]);
            }
        }
}

// ---------------- fused edge + stats + PNA + Wo + LN: 8 nodes / 256-thread block ----------------
// R8: __launch_bounds__(256,2) (R7's (256,4) halved the reg budget -> scratch spills,
// 2.4 GB HBM traffic). GEMM split into K-pass then V-pass to halve acc live range.

__global__ __launch_bounds__(256, 2) void edge_fused(
        const float* __restrict__ E, const float* __restrict__ R,
        const unsigned short* __restrict__ qp,
        const unsigned short* __restrict__ Bhi, const unsigned short* __restrict__ Blo,
        const unsigned short* __restrict__ Wop,
        const float* __restrict__ deg,
        const int* __restrict__ src, const int* __restrict__ rel,
        const int* __restrict__ dst, const int* __restrict__ perm,
        const int* __restrict__ off,
        const float* __restrict__ q, const float* __restrict__ ln_g,
        const float* __restrict__ ln_b, float* __restrict__ out,
        int nNodes, int nE) {

    __shared__ __align__(16) unsigned short msgb[2][32][128];  // 16KB; reused: V f32 [32][128]; then aggb bf16 [16][512]
    __shared__ __align__(16) unsigned short Kb[32][128];       // 8KB; reused: hb f32 [8][128]
    __shared__ float alph[32][8];                              // sigmoid * deg
    __shared__ __align__(16) unsigned short qpl[8][128];
    __shared__ float sdeg[32];
    __shared__ int sdst[32];
    __shared__ int noff[9];

    int t = threadIdx.x;
    int n0 = blockIdx.x * 8;

    if (t < 9) {
        int idx = n0 + t;
        noff[t] = (idx < nNodes) ? off[idx] : nE;
    }
    {
        int ln = t >> 5, g = t & 31;
        int node = n0 + ln;
        ushort4 v;
        if (node < nNodes) v = *(const ushort4*)(qp + (size_t)node * 128 + g * 4);
        else { v.x = 0; v.y = 0; v.z = 0; v.w = 0; }
        *(ushort4*)(&qpl[ln][g * 4]) = v;
    }
    __syncthreads();

    int eb = noff[0], ee = noff[8];

    int lnS = t >> 5, gS = t & 31;
    float sSx = 0.f, sSy = 0.f, sSz = 0.f, sSw = 0.f;
    float sQx = 0.f, sQy = 0.f, sQz = 0.f, sQw = 0.f;
    float sXx = -FLT_BIG, sXy = -FLT_BIG, sXz = -FLT_BIG, sXw = -FLT_BIG;
    float sNx = FLT_BIG, sNy = FLT_BIG, sNz = FLT_BIG, sNw = FLT_BIG;

    int w = t >> 6, l = t & 63;
    int lrow = l & 15, lk = l >> 4;
    float* Vlds = (float*)msgb;

    for (int c0 = eb; c0 < ee; c0 += 32) {
        // ---- stage msg (hi/lo bf16) ----
        {
            int e = t >> 3, sub = t & 7;
            int ei = c0 + e;
            bool ok = (ei < ee);
            int p = ok ? perm[ei] : 0;
            if (sub == 0) sdst[e] = ok ? (dst[p] - n0) : -1;
            if (sub == 1) sdeg[e] = ok ? deg[p] : 0.f;
            const float* Erow = E + (size_t)(ok ? src[p] : 0) * 128;
            const float* Rrow = R + (size_t)(ok ? rel[p] : 0) * 128;
#pragma unroll
            for (int cc = 0; cc < 2; ++cc) {
                int chunk = sub * 2 + cc;
                U8 H, L;
                if (ok) {
                    float4 a0 = *(const float4*)(Erow + chunk * 8);
                    float4 a1 = *(const float4*)(Erow + chunk * 8 + 4);
                    float4 b0 = *(const float4*)(Rrow + chunk * 8);
                    float4 b1 = *(const float4*)(Rrow + chunk * 8 + 4);
                    float m[8] = {a0.x * b0.x, a0.y * b0.y, a0.z * b0.z, a0.w * b0.w,
                                  a1.x * b1.x, a1.y * b1.y, a1.z * b1.z, a1.w * b1.w};
#pragma unroll
                    for (int j = 0; j < 8; ++j) {
                        unsigned short h = f2bf(m[j]);
                        H.u[j] = h; L.u[j] = f2bf(m[j] - bf2f(h));
                    }
                } else {
#pragma unroll
                    for (int j = 0; j < 8; ++j) { H.u[j] = 0; L.u[j] = 0; }
                }
                int sc = chunk ^ (e & 7);
                *reinterpret_cast<short8*>(&msgb[0][e][sc * 8]) = H.v;
                *reinterpret_cast<short8*>(&msgb[1][e][sc * 8]) = L.v;
            }
        }
        __syncthreads();

        // ---- GEMM pass 1: K tiles (ntg 0..7), 3-pass hi/lo ----
        {
            floatx4 acc[2][2];
#pragma unroll
            for (int mt = 0; mt < 2; ++mt)
#pragma unroll
                for (int n = 0; n < 2; ++n) acc[mt][n] = (floatx4){0.f, 0.f, 0.f, 0.f};
            for (int ks = 0; ks < 4; ++ks) {
                short8 ah[2], al[2];
#pragma unroll
                for (int mt = 0; mt < 2; ++mt) {
                    int row = mt * 16 + lrow;
                    int sc = (ks * 4 + lk) ^ (row & 7);
                    ah[mt] = *reinterpret_cast<const short8*>(&msgb[0][row][sc * 8]);
                    al[mt] = *reinterpret_cast<const short8*>(&msgb[1][row][sc * 8]);
                }
#pragma unroll
                for (int ntl = 0; ntl < 2; ++ntl) {
                    int ntg = w * 2 + ntl;
                    size_t bo = ((size_t)(ntg * 4 + ks) * 64 + l) * 8;
                    short8 bh = *reinterpret_cast<const short8*>(Bhi + bo);
                    short8 bl = *reinterpret_cast<const short8*>(Blo + bo);
#pragma unroll
                    for (int mt = 0; mt < 2; ++mt) {
                        acc[mt][ntl] = __builtin_amdgcn_mfma_f32_16x16x32_bf16(ah[mt], bh, acc[mt][ntl], 0, 0, 0);
                        acc[mt][ntl] = __builtin_amdgcn_mfma_f32_16x16x32_bf16(al[mt], bh, acc[mt][ntl], 0, 0, 0);
                        acc[mt][ntl] = __builtin_amdgcn_mfma_f32_16x16x32_bf16(ah[mt], bl, acc[mt][ntl], 0, 0, 0);
                    }
                }
            }
            // K writeback (bf16 into Kb; Kb not read until after next barrier)
#pragma unroll
            for (int mt = 0; mt < 2; ++mt)
#pragma unroll
                for (int ntl = 0; ntl < 2; ++ntl) {
                    int col = (w * 2 + ntl) * 16 + lrow;
#pragma unroll
                    for (int r = 0; r < 4; ++r) {
                        int row = mt * 16 + lk * 4 + r;
                        int key = ((row >> 2) & 3) << 4;
                        Kb[row][col ^ key] = f2bf(acc[mt][ntl][r]);
                    }
                }
        }

        // ---- GEMM pass 2: V tiles (ntg 8..15), 3-pass hi/lo ----
        {
            floatx4 acc[2][2];
#pragma unroll
            for (int mt = 0; mt < 2; ++mt)
#pragma unroll
                for (int n = 0; n < 2; ++n) acc[mt][n] = (floatx4){0.f, 0.f, 0.f, 0.f};
            for (int ks = 0; ks < 4; ++ks) {
                short8 ah[2], al[2];
#pragma unroll
                for (int mt = 0; mt < 2; ++mt) {
                    int row = mt * 16 + lrow;
                    int sc = (ks * 4 + lk) ^ (row & 7);
                    ah[mt] = *reinterpret_cast<const short8*>(&msgb[0][row][sc * 8]);
                    al[mt] = *reinterpret_cast<const short8*>(&msgb[1][row][sc * 8]);
                }
#pragma unroll
                for (int ntl = 0; ntl < 2; ++ntl) {
                    int ntg = 8 + w * 2 + ntl;
                    size_t bo = ((size_t)(ntg * 4 + ks) * 64 + l) * 8;
                    short8 bh = *reinterpret_cast<const short8*>(Bhi + bo);
                    short8 bl = *reinterpret_cast<const short8*>(Blo + bo);
#pragma unroll
                    for (int mt = 0; mt < 2; ++mt) {
                        acc[mt][ntl] = __builtin_amdgcn_mfma_f32_16x16x32_bf16(ah[mt], bh, acc[mt][ntl], 0, 0, 0);
                        acc[mt][ntl] = __builtin_amdgcn_mfma_f32_16x16x32_bf16(al[mt], bh, acc[mt][ntl], 0, 0, 0);
                        acc[mt][ntl] = __builtin_amdgcn_mfma_f32_16x16x32_bf16(ah[mt], bl, acc[mt][ntl], 0, 0, 0);
                    }
                }
            }
            __syncthreads();   // all msgb A-reads done; safe to overwrite with V
            // V writeback (f32 overlaying msgb)
#pragma unroll
            for (int mt = 0; mt < 2; ++mt)
#pragma unroll
                for (int ntl = 0; ntl < 2; ++ntl) {
                    int col = (w * 2 + ntl) * 16 + lrow;   // V logical col 0..127
#pragma unroll
                    for (int r = 0; r < 4; ++r) {
                        int row = mt * 16 + lk * 4 + r;
                        int key = ((row >> 2) & 3) << 4;
                        Vlds[row * 128 + (col ^ key)] = acc[mt][ntl][r];
                    }
                }
        }
        __syncthreads();

        // ---- alpha: thread = (edge, head) ----
        {
            int e = t >> 3, h = t & 7;
            int ln = sdst[e];
            float wv = 0.f;
            if (ln >= 0) {
                int key = ((e >> 2) & 3) << 4;
                int cb = (h * 16) ^ key;
                U8 k0, k1, q0, q1;
                k0.v = *reinterpret_cast<const short8*>(&Kb[e][cb]);
                k1.v = *reinterpret_cast<const short8*>(&Kb[e][cb + 8]);
                q0.v = *reinterpret_cast<const short8*>(&qpl[ln][h * 16]);
                q1.v = *reinterpret_cast<const short8*>(&qpl[ln][h * 16 + 8]);
                float a = 0.f;
#pragma unroll
                for (int j = 0; j < 8; ++j) {
                    a = fmaf(bf2f(k0.u[j]), bf2f(q0.u[j]), a);
                    a = fmaf(bf2f(k1.u[j]), bf2f(q1.u[j]), a);
                }
                float alphav = a * 0.25f;                 // / sqrt(16)
                wv = sdeg[e] / (1.f + __expf(-alphav));   // sigmoid * deg
            }
            alph[e][h] = wv;
        }
        __syncthreads();

        // ---- stats: thread = (node lnS, cols 4gS..4gS+3) ----
        {
            int lo = max(noff[lnS], c0);
            int hi = min(noff[lnS + 1], c0 + 32);
            for (int ei2 = lo; ei2 < hi; ++ei2) {
                int el = ei2 - c0;
                int key = ((el >> 2) & 3) << 4;
                float4 v4 = *(const float4*)(Vlds + el * 128 + ((gS * 4) ^ key));
                float aa = alph[el][gS >> 2];
                float xx = v4.x * aa, xy = v4.y * aa, xz = v4.z * aa, xw = v4.w * aa;
                sSx += xx; sSy += xy; sSz += xz; sSw += xw;
                sQx = fmaf(xx, xx, sQx); sQy = fmaf(xy, xy, sQy);
                sQz = fmaf(xz, xz, sQz); sQw = fmaf(xw, xw, sQw);
                sXx = fmaxf(sXx, xx); sXy = fmaxf(sXy, xy);
                sXz = fmaxf(sXz, xz); sXw = fmaxf(sXw, xw);
                sNx = fminf(sNx, xx); sNy = fminf(sNy, xy);
                sNz = fminf(sNz, xz); sNw = fminf(sNw, xw);
            }
        }
        __syncthreads();
    }

    // ---- build agg tile (bf16, MFMA-A layout, rows 8..15 zero) ----
    unsigned short* aggb = (unsigned short*)msgb;   // [16][512]
    *reinterpret_cast<short8*>(aggb + 8 * 512 + t * 16) = (short8){0,0,0,0,0,0,0,0};
    *reinterpret_cast<short8*>(aggb + 8 * 512 + t * 16 + 8) = (short8){0,0,0,0,0,0,0,0};
    {
        int c = noff[lnS + 1] - noff[lnS];
        float invc = (c > 0) ? 1.f / (float)c : 0.f;
        float vals[4][4];
        vals[0][0] = sSx * invc; vals[0][1] = sSy * invc; vals[0][2] = sSz * invc; vals[0][3] = sSw * invc;
        vals[1][0] = (c > 0) ? sXx : 0.f; vals[1][1] = (c > 0) ? sXy : 0.f;
        vals[1][2] = (c > 0) ? sXz : 0.f; vals[1][3] = (c > 0) ? sXw : 0.f;
        vals[2][0] = (c > 0) ? sNx : 0.f; vals[2][1] = (c > 0) ? sNy : 0.f;
        vals[2][2] = (c > 0) ? sNz : 0.f; vals[2][3] = (c > 0) ? sNw : 0.f;
        vals[3][0] = sqrtf(fmaxf(sQx - sSx * sSx, 1e-8f));
        vals[3][1] = sqrtf(fmaxf(sQy - sSy * sSy, 1e-8f));
        vals[3][2] = sqrtf(fmaxf(sQz - sSz * sSz, 1e-8f));
        vals[3][3] = sqrtf(fmaxf(sQw - sSw * sSw, 1e-8f));
#pragma unroll
        for (int s = 0; s < 4; ++s) {
            int chunk = s * 16 + (gS >> 1);
            int pos = ((chunk ^ (lnS & 7)) << 3) + ((gS & 1) * 4);
            ushort4 o;
            o.x = f2bf(vals[s][0]); o.y = f2bf(vals[s][1]);
            o.z = f2bf(vals[s][2]); o.w = f2bf(vals[s][3]);
            *(ushort4*)(aggb + lnS * 512 + pos) = o;
        }
    }
    __syncthreads();

    // ---- Wo MFMA: m-tile 16 (rows 0..7 real), n = 128, K = 512 ----
    floatx4 acc2[2];
    acc2[0] = (floatx4){0.f, 0.f, 0.f, 0.f};
    acc2[1] = (floatx4){0.f, 0.f, 0.f, 0.f};
    for (int ks = 0; ks < 16; ++ks) {
        int sc = (ks * 4 + lk) ^ (lrow & 7);
        short8 a = *reinterpret_cast<const short8*>(aggb + lrow * 512 + sc * 8);
#pragma unroll
        for (int ntl = 0; ntl < 2; ++ntl) {
            int ntg = w * 2 + ntl;
            short8 b = *reinterpret_cast<const short8*>(Wop + ((size_t)(ntg * 16 + ks) * 64 + l) * 8);
            acc2[ntl] = __builtin_amdgcn_mfma_f32_16x16x32_bf16(a, b, acc2[ntl], 0, 0, 0);
        }
    }

    // ---- residual into hb (overlay Kb region) ----
    float* hb = (float*)Kb;   // [8][128]
#pragma unroll
    for (int ntl = 0; ntl < 2; ++ntl) {
        int col = (w * 2 + ntl) * 16 + lrow;
#pragma unroll
        for (int r = 0; r < 4; ++r) {
            int row = lk * 4 + r;
            if (row < 8) {
                int node = n0 + row;
                float h = acc2[ntl][r] + ((node < nNodes) ? q[(size_t)node * 128 + col] : 0.f);
                hb[row * 128 + col] = h;
            }
        }
    }
    __syncthreads();

    // ---- LayerNorm + out ----
    {
        int node = n0 + lnS;
        float4 h4 = *(const float4*)(hb + lnS * 128 + gS * 4);
        float ps = h4.x + h4.y + h4.z + h4.w;
        ps += __shfl_xor(ps, 1);
        ps += __shfl_xor(ps, 2);
        ps += __shfl_xor(ps, 4);
        ps += __shfl_xor(ps, 8);
        ps += __shfl_xor(ps, 16);
        float mu = ps * (1.f / 128.f);
        float dx = h4.x - mu, dy = h4.y - mu, dz = h4.z - mu, dw = h4.w - mu;
        float pv = dx * dx + dy * dy + dz * dz + dw * dw;
        pv += __shfl_xor(pv, 1);
        pv += __shfl_xor(pv, 2);
        pv += __shfl_xor(pv, 4);
        pv += __shfl_xor(pv, 8);
        pv += __shfl_xor(pv, 16);
        float rr = rsqrtf(pv * (1.f / 128.f) + 1e-5f);
        if (node < nNodes) {
            float4 gv = *(const float4*)(ln_g + gS * 4);
            float4 bv = *(const float4*)(ln_b + gS * 4);
            float4 o;
            o.x = dx * rr * gv.x + bv.x;
            o.y = dy * rr * gv.y + bv.y;
            o.z = dz * rr * gv.z + bv.z;
            o.w = dw * rr * gv.w + bv.w;
            *(float4*)(out + (size_t)node * 128 + gS * 4) = o;
        }
    }
}

// ---------------- launch ----------------

extern "C" void kernel_launch(void* const* d_in, const int* in_sizes, int n_in,
                              void* d_out, int out_size, void* d_ws, size_t ws_size,
                              hipStream_t stream) {
    const float* q    = (const float*)d_in[0];
    const float* E    = (const float*)d_in[1];
    const float* R    = (const float*)d_in[2];
    const float* Wq   = (const float*)d_in[3];
    const float* Wk   = (const float*)d_in[4];
    const float* Wv   = (const float*)d_in[5];
    const float* Wo   = (const float*)d_in[6];
    const float* ln_g = (const float*)d_in[7];
    const float* ln_b = (const float*)d_in[8];
    const float* deg  = (const float*)d_in[9];
    const int* src    = (const int*)d_in[10];
    const int* rel    = (const int*)d_in[11];
    const int* dst    = (const int*)d_in[12];
    int nNodes = in_sizes[0] / D;   // 50000
    int nEdges = in_sizes[10];      // 500000
    float* out = (float*)d_out;

    // w is char*: all increments in BYTES.
    char* w = (char*)d_ws;
    size_t nd = (size_t)nNodes * D;
    unsigned short* qp = (unsigned short*)w; w += nd * 2;                    // 12.8 MB
    int* cnt      = (int*)w;                 w += (size_t)nNodes * 4;
    int* off      = (int*)w;                 w += (size_t)nNodes * 4;
    int* fill     = (int*)w;                 w += (size_t)nNodes * 4;
    int* perm     = (int*)w;                 w += (size_t)nEdges * 4;        // 2 MB
    int* chunksum = (int*)w;                 w += 256 * 4;
    int* chunkoff = (int*)w;                 w += 256 * 4;
    unsigned short* Wp_hi  = (unsigned short*)w; w += 16 * 4 * 64 * 8 * 2;   // 64 KB
    unsigned short* Wp_lo  = (unsigned short*)w; w += 16 * 4 * 64 * 8 * 2;
    unsigned short* Wqp_hi = (unsigned short*)w; w += 8 * 4 * 64 * 8 * 2;    // 32 KB
    unsigned short* Wqp_lo = (unsigned short*)w; w += 8 * 4 * 64 * 8 * 2;
    unsigned short* Wop    = (unsigned short*)w; w += 8 * 16 * 64 * 8 * 2;   // 128 KB
    // total ~15.8 MB

    int nChunks = (nNodes + 255) / 256;

    zero2_kernel<<<(nNodes + 255) / 256, 256, 0, stream>>>(cnt, fill, nNodes);
    hist_kernel<<<(nEdges + 255) / 256, 256, 0, stream>>>(dst, cnt, nEdges);
    scanA_kernel<<<nChunks, 256, 0, stream>>>(cnt, chunksum, nNodes);
    scanB_kernel<<<1, 256, 0, stream>>>(chunksum, chunkoff, nChunks);
    scanC_kernel<<<nChunks, 256, 0, stream>>>(cnt, chunkoff, off, nNodes);
    scatter_kernel<<<(nEdges + 255) / 256, 256, 0, stream>>>(dst, off, fill, perm, nEdges);

    pack_kernel<<<16 * 4, 64, 0, stream>>>(Wk, Wv, 128, Wp_hi, Wp_lo);
    pack_kernel<<<8 * 4, 64, 0, stream>>>(Wq, Wq, 128, Wqp_hi, Wqp_lo);
    pack_kernel<<<8 * 16, 64, 0, stream>>>(Wo, Wo, 512, Wop, (unsigned short*)nullptr);

    qproj_mfma<<<(nNodes + 63) / 64, 256, 0, stream>>>(q, Wqp_hi, Wqp_lo, qp, nNodes);
    edge_fused<<<(nNodes + 7) / 8, 256, 0, stream>>>(E, R, qp, Wp_hi, Wp_lo, Wop, deg,
                                                     src, rel, dst, perm, off,
                                                     q, ln_g, ln_b, out, nNodes, nEdges);
}